// Round 1
// baseline (165.867 us; speedup 1.0000x reference)
//
#include <hip/hip_runtime.h>
#include <math.h>

#define N_NODES 10000
#define N_EDGES 160000
#define D 256

// ---------------- CSR build ----------------

__global__ void k_zero(int* __restrict__ deg, int* __restrict__ cursor, int n) {
    int i = blockIdx.x * blockDim.x + threadIdx.x;
    if (i < n) { deg[i] = 0; cursor[i] = 0; }
}

__global__ void k_deg(const int* __restrict__ row, int* __restrict__ deg, int e) {
    int i = blockIdx.x * blockDim.x + threadIdx.x;
    if (i < e) atomicAdd(&deg[row[i]], 1);
}

// single-block exclusive scan over N_NODES degrees
__global__ void k_scan(const int* __restrict__ deg, int* __restrict__ offsets) {
    __shared__ int partial[1024];
    const int n = N_NODES;
    int tid = threadIdx.x;
    const int chunk = (n + 1023) / 1024;
    int start = tid * chunk; if (start > n) start = n;
    int end = start + chunk; if (end > n) end = n;
    int s = 0;
    for (int i = start; i < end; ++i) s += deg[i];
    partial[tid] = s;
    __syncthreads();
    for (int off = 1; off < 1024; off <<= 1) {
        int v = (tid >= off) ? partial[tid - off] : 0;
        __syncthreads();
        partial[tid] += v;
        __syncthreads();
    }
    int base = (tid == 0) ? 0 : partial[tid - 1];
    for (int i = start; i < end; ++i) { offsets[i] = base; base += deg[i]; }
    if (tid == 1023) offsets[n] = partial[1023];
}

__global__ void k_fill(const int* __restrict__ row, const int* __restrict__ col,
                       const int* __restrict__ offsets, int* __restrict__ cursor,
                       int* __restrict__ csr_col, int e) {
    int i = blockIdx.x * blockDim.x + threadIdx.x;
    if (i < e) {
        int r = row[i];
        int p = atomicAdd(&cursor[r], 1);
        csr_col[offsets[r] + p] = col[i];
    }
}

// ---------------- neighbor mean ----------------
// one block (256 threads) per node; thread d owns dim d
__global__ void k_neigh_mean(const float* __restrict__ X,
                             const int* __restrict__ offsets,
                             const int* __restrict__ csr_col,
                             float* __restrict__ M) {
    int i = blockIdx.x;
    int d = threadIdx.x;
    int st = offsets[i], en = offsets[i + 1];
    float s = 0.f;
    for (int e = st; e < en; ++e) {
        int j = csr_col[e];
        s += X[j * D + d];
    }
    float denom = (float)((en - st) > 1 ? (en - st) : 1);
    M[i * D + d] = s / denom;
}

// ---------------- fused GEMM: H = relu([X|M] @ [Wr;Wn] + b) ----------------
#define BM 64
#define BN 64
#define BK 16

__global__ __launch_bounds__(256) void k_gemm(
    const float* __restrict__ X, const float* __restrict__ M,
    const float* __restrict__ Wr, const float* __restrict__ Wn,
    const float* __restrict__ bias, float* __restrict__ H) {
    __shared__ float As[BK][BM + 1];
    __shared__ float Bs[BK][BN];

    int tid = threadIdx.x;
    int tx = tid & 15;        // output col group
    int ty = tid >> 4;        // output row group
    int row0 = blockIdx.x * BM;
    int col0 = blockIdx.y * BN;

    float acc[4][4] = {{0.f}};

    for (int kk = 0; kk < 2 * D; kk += BK) {
        // load A tile (64 rows x 16 k), float4 per thread
        {
            int rl = tid >> 2, kq = tid & 3;
            int row = row0 + rl;
            int rc = row < N_NODES ? row : N_NODES - 1;
            int kbase = kk + kq * 4;
            const float* src = (kbase < D) ? (X + (size_t)rc * D + kbase)
                                           : (M + (size_t)rc * D + (kbase - D));
            float4 v = *(const float4*)src;
            As[kq * 4 + 0][rl] = v.x;
            As[kq * 4 + 1][rl] = v.y;
            As[kq * 4 + 2][rl] = v.z;
            As[kq * 4 + 3][rl] = v.w;
        }
        // load B tile (16 k x 64 cols), float4 per thread
        {
            int k = tid >> 4, cq = tid & 15;
            int kb = kk + k;
            const float* src = (kb < D) ? (Wr + (size_t)kb * D + col0 + cq * 4)
                                        : (Wn + (size_t)(kb - D) * D + col0 + cq * 4);
            *(float4*)&Bs[k][cq * 4] = *(const float4*)src;
        }
        __syncthreads();

        #pragma unroll
        for (int k = 0; k < BK; ++k) {
            float av[4], bv[4];
            #pragma unroll
            for (int i = 0; i < 4; ++i) av[i] = As[k][ty * 4 + i];
            float4 b4 = *(const float4*)&Bs[k][tx * 4];
            bv[0] = b4.x; bv[1] = b4.y; bv[2] = b4.z; bv[3] = b4.w;
            #pragma unroll
            for (int i = 0; i < 4; ++i)
                #pragma unroll
                for (int j = 0; j < 4; ++j)
                    acc[i][j] += av[i] * bv[j];
        }
        __syncthreads();
    }

    // epilogue: add bias, relu, store
    #pragma unroll
    for (int i = 0; i < 4; ++i) {
        int row = row0 + ty * 4 + i;
        if (row < N_NODES) {
            #pragma unroll
            for (int j = 0; j < 4; ++j) {
                int c = col0 + tx * 4 + j;
                float h = acc[i][j] + bias[c];
                H[(size_t)row * D + c] = h > 0.f ? h : 0.f;
            }
        }
    }
}

// ---------------- edge diffs -> scatter-mean -> tanh ----------------
// one block (256 threads) per node; thread d owns dim d
__global__ void k_out(const float* __restrict__ H,
                      const int* __restrict__ offsets,
                      const int* __restrict__ csr_col,
                      float* __restrict__ out) {
    int i = blockIdx.x;
    int d = threadIdx.x;
    float hi = H[(size_t)i * D + d];
    int st = offsets[i], en = offsets[i + 1];
    float acc = 0.f;
    for (int e = st; e < en; ++e) {
        int j = csr_col[e];
        float t = hi - H[(size_t)j * D + d];
        acc += t * t;   // |.|^2.0
    }
    float denom = (float)((en - st) > 1 ? (en - st) : 1);
    out[(size_t)i * D + d] = tanhf(acc / denom);
}

// ---------------- launch ----------------

extern "C" void kernel_launch(void* const* d_in, const int* in_sizes, int n_in,
                              void* d_out, int out_size, void* d_ws, size_t ws_size,
                              hipStream_t stream) {
    const float* X    = (const float*)d_in[0];
    const int*   edge = (const int*)d_in[1];   // [2][E]: row=edge[0:E], col=edge[E:2E]
    const float* Wr   = (const float*)d_in[2];
    const float* Wn   = (const float*)d_in[3];
    const float* bias = (const float*)d_in[4];
    float* out = (float*)d_out;

    char* ws = (char*)d_ws;
    size_t off = 0;
    auto alloc = [&](size_t bytes) -> void* {
        void* p = ws + off;
        off += (bytes + 255) & ~(size_t)255;
        return p;
    };
    int*   deg     = (int*)alloc(sizeof(int) * N_NODES);
    int*   cursor  = (int*)alloc(sizeof(int) * N_NODES);
    int*   offsets = (int*)alloc(sizeof(int) * (N_NODES + 1));
    int*   csr_col = (int*)alloc(sizeof(int) * N_EDGES);
    float* M       = (float*)alloc(sizeof(float) * (size_t)N_NODES * D);
    float* H       = (float*)alloc(sizeof(float) * (size_t)N_NODES * D);

    const int* row = edge;
    const int* col = edge + N_EDGES;

    k_zero<<<(N_NODES + 255) / 256, 256, 0, stream>>>(deg, cursor, N_NODES);
    k_deg<<<(N_EDGES + 255) / 256, 256, 0, stream>>>(row, deg, N_EDGES);
    k_scan<<<1, 1024, 0, stream>>>(deg, offsets);
    k_fill<<<(N_EDGES + 255) / 256, 256, 0, stream>>>(row, col, offsets, cursor,
                                                      csr_col, N_EDGES);
    k_neigh_mean<<<N_NODES, 256, 0, stream>>>(X, offsets, csr_col, M);

    dim3 ggrid((N_NODES + BM - 1) / BM, D / BN);
    k_gemm<<<ggrid, 256, 0, stream>>>(X, M, Wr, Wn, bias, H);

    k_out<<<N_NODES, 256, 0, stream>>>(H, offsets, csr_col, out);
}

// Round 2
// 124.133 us; speedup vs baseline: 1.3362x; 1.3362x over previous
//
#include <hip/hip_runtime.h>
#include <math.h>

#define N_NODES 10000
#define N_EDGES 160000
#define D 256
#define KDIM 512   // 2*D

typedef short bf16x8 __attribute__((ext_vector_type(8)));
typedef float f32x4 __attribute__((ext_vector_type(4)));
typedef unsigned short ushort_t;

__device__ __forceinline__ ushort_t f2bf(float f) {
    unsigned u = __builtin_bit_cast(unsigned, f);
    unsigned r = (u + 0x7fffu + ((u >> 16) & 1u)) >> 16;
    return (ushort_t)r;
}

// ---------------- CSR build ----------------

__global__ void k_zero(int* __restrict__ deg, int* __restrict__ cursor, int n) {
    int i = blockIdx.x * blockDim.x + threadIdx.x;
    if (i < n) { deg[i] = 0; cursor[i] = 0; }
}

__global__ void k_deg(const int* __restrict__ row, int* __restrict__ deg, int e) {
    int i = blockIdx.x * blockDim.x + threadIdx.x;
    if (i < e) atomicAdd(&deg[row[i]], 1);
}

__global__ void k_scan(const int* __restrict__ deg, int* __restrict__ offsets) {
    __shared__ int partial[1024];
    const int n = N_NODES;
    int tid = threadIdx.x;
    const int chunk = (n + 1023) / 1024;
    int start = tid * chunk; if (start > n) start = n;
    int end = start + chunk; if (end > n) end = n;
    int s = 0;
    for (int i = start; i < end; ++i) s += deg[i];
    partial[tid] = s;
    __syncthreads();
    for (int off = 1; off < 1024; off <<= 1) {
        int v = (tid >= off) ? partial[tid - off] : 0;
        __syncthreads();
        partial[tid] += v;
        __syncthreads();
    }
    int base = (tid == 0) ? 0 : partial[tid - 1];
    for (int i = start; i < end; ++i) { offsets[i] = base; base += deg[i]; }
    if (tid == 1023) offsets[n] = partial[1023];
}

__global__ void k_fill(const int* __restrict__ row, const int* __restrict__ col,
                       const int* __restrict__ offsets, int* __restrict__ cursor,
                       int* __restrict__ csr_col, int e) {
    int i = blockIdx.x * blockDim.x + threadIdx.x;
    if (i < e) {
        int r = row[i];
        int p = atomicAdd(&cursor[r], 1);
        csr_col[offsets[r] + p] = col[i];
    }
}

// ---------------- cast X into A[:, 0:256] (bf16) ----------------
// A is [N_NODES][512] bf16: cols 0..255 = X, cols 256..511 = neigh_mean
__global__ void k_castX(const float* __restrict__ X, ushort_t* __restrict__ A) {
    int t = blockIdx.x * blockDim.x + threadIdx.x;   // 640000 threads
    int node = t >> 6, lane = t & 63;
    if (node >= N_NODES) return;
    float4 v = *(const float4*)(X + (size_t)node * D + lane * 4);
    ushort4 o = make_ushort4(f2bf(v.x), f2bf(v.y), f2bf(v.z), f2bf(v.w));
    *(ushort4*)(A + (size_t)node * KDIM + lane * 4) = o;
}

// ---------------- build B^T: Wb[n][k], n in [0,256), k in [0,512) ----------------
// LDS 32x32 tile transpose. grid: (512/32, 256/32)
__global__ void k_prepW(const float* __restrict__ Wr, const float* __restrict__ Wn,
                        ushort_t* __restrict__ Wb) {
    __shared__ float tile[32][33];
    int k0 = blockIdx.x * 32, n0 = blockIdx.y * 32;
    int t = threadIdx.x;
    {
        int r = t >> 3, c4 = t & 7;          // r: k-row 0..31, c4: 4-col group
        int k = k0 + r;
        const float* src = (k < D) ? (Wr + (size_t)k * D + n0 + c4 * 4)
                                   : (Wn + (size_t)(k - D) * D + n0 + c4 * 4);
        float4 v = *(const float4*)src;
        tile[r][c4 * 4 + 0] = v.x; tile[r][c4 * 4 + 1] = v.y;
        tile[r][c4 * 4 + 2] = v.z; tile[r][c4 * 4 + 3] = v.w;
    }
    __syncthreads();
    {
        int n = t >> 3, kq = t & 7;          // n: 0..31, kq: 4-k group
        ushort4 o = make_ushort4(f2bf(tile[kq * 4 + 0][n]), f2bf(tile[kq * 4 + 1][n]),
                                 f2bf(tile[kq * 4 + 2][n]), f2bf(tile[kq * 4 + 3][n]));
        *(ushort4*)(Wb + (size_t)(n0 + n) * KDIM + k0 + kq * 4) = o;
    }
}

// ---------------- neighbor mean -> A[:, 256:512] (bf16) ----------------
// one wave per node, lane owns 4 dims (float4)
__global__ void k_neigh_mean(const float* __restrict__ X,
                             const int* __restrict__ offsets,
                             const int* __restrict__ csr_col,
                             ushort_t* __restrict__ A) {
    int node = blockIdx.x * 4 + (threadIdx.x >> 6);
    int lane = threadIdx.x & 63;
    if (node >= N_NODES) return;
    int st = offsets[node], en = offsets[node + 1];
    float ax = 0.f, ay = 0.f, az = 0.f, aw = 0.f;
    for (int e = st; e < en; ++e) {
        int j = csr_col[e];
        float4 v = *(const float4*)(X + (size_t)j * D + lane * 4);
        ax += v.x; ay += v.y; az += v.z; aw += v.w;
    }
    float inv = 1.f / (float)((en - st) > 1 ? (en - st) : 1);
    ushort4 o = make_ushort4(f2bf(ax * inv), f2bf(ay * inv), f2bf(az * inv), f2bf(aw * inv));
    *(ushort4*)(A + (size_t)node * KDIM + D + lane * 4) = o;
}

// ---------------- MFMA GEMM: H = relu(A @ Wb^T + b) ----------------
// A [N][512] bf16, Wb [256][512] bf16 (n-major, k-contiguous), H [N][256] f32
#define BM 128
#define BN 128
#define BK 32
#define LDK 40   // padded LDS k-stride (ushorts): 80B -> stride of 20 banks

__global__ __launch_bounds__(256) void k_gemm(
    const ushort_t* __restrict__ A, const ushort_t* __restrict__ Wb,
    const float* __restrict__ bias, float* __restrict__ H) {
    __shared__ ushort_t As[BM][LDK];
    __shared__ ushort_t Bs[BN][LDK];

    int tid = threadIdx.x;
    int lane = tid & 63;
    int wave = tid >> 6;          // 0..3
    int wm = wave >> 1;           // 0..1  (row half)
    int wn = wave & 1;            // 0..1  (col half)
    int row0 = blockIdx.x * BM;
    int col0 = blockIdx.y * BN;

    f32x4 acc[4][4];
    #pragma unroll
    for (int i = 0; i < 4; ++i)
        #pragma unroll
        for (int j = 0; j < 4; ++j)
            acc[i][j] = (f32x4){0.f, 0.f, 0.f, 0.f};

    int r_a = tid >> 2;           // 0..63
    int kq = tid & 3;             // 16B k-group

    for (int kk = 0; kk < KDIM; kk += BK) {
        // issue global loads (A: 2x16B, B: 2x16B per thread)
        int ga0 = row0 + r_a;      if (ga0 >= N_NODES) ga0 = N_NODES - 1;
        int ga1 = row0 + r_a + 64; if (ga1 >= N_NODES) ga1 = N_NODES - 1;
        ushort4 a0 = *(const ushort4*)(A + (size_t)ga0 * KDIM + kk + kq * 8);
        ushort4 a1 = *(const ushort4*)(A + (size_t)ga0 * KDIM + kk + kq * 8 + 4);
        ushort4 a2 = *(const ushort4*)(A + (size_t)ga1 * KDIM + kk + kq * 8);
        ushort4 a3 = *(const ushort4*)(A + (size_t)ga1 * KDIM + kk + kq * 8 + 4);
        ushort4 b0 = *(const ushort4*)(Wb + (size_t)(col0 + r_a) * KDIM + kk + kq * 8);
        ushort4 b1 = *(const ushort4*)(Wb + (size_t)(col0 + r_a) * KDIM + kk + kq * 8 + 4);
        ushort4 b2 = *(const ushort4*)(Wb + (size_t)(col0 + r_a + 64) * KDIM + kk + kq * 8);
        ushort4 b3 = *(const ushort4*)(Wb + (size_t)(col0 + r_a + 64) * KDIM + kk + kq * 8 + 4);

        __syncthreads();   // previous iteration's LDS reads complete
        *(ushort4*)&As[r_a][kq * 8]          = a0;
        *(ushort4*)&As[r_a][kq * 8 + 4]      = a1;
        *(ushort4*)&As[r_a + 64][kq * 8]     = a2;
        *(ushort4*)&As[r_a + 64][kq * 8 + 4] = a3;
        *(ushort4*)&Bs[r_a][kq * 8]          = b0;
        *(ushort4*)&Bs[r_a][kq * 8 + 4]      = b1;
        *(ushort4*)&Bs[r_a + 64][kq * 8]     = b2;
        *(ushort4*)&Bs[r_a + 64][kq * 8 + 4] = b3;
        __syncthreads();

        // fragments: row/col = lane&15, k-group = (lane>>4)*8
        int fr = lane & 15, fg = (lane >> 4) * 8;
        bf16x8 aF[4], bF[4];
        #pragma unroll
        for (int mf = 0; mf < 4; ++mf)
            aF[mf] = *(const bf16x8*)&As[wm * 64 + mf * 16 + fr][fg];
        #pragma unroll
        for (int nf = 0; nf < 4; ++nf)
            bF[nf] = *(const bf16x8*)&Bs[wn * 64 + nf * 16 + fr][fg];
        #pragma unroll
        for (int mf = 0; mf < 4; ++mf)
            #pragma unroll
            for (int nf = 0; nf < 4; ++nf)
                acc[mf][nf] = __builtin_amdgcn_mfma_f32_16x16x32_bf16(
                    aF[mf], bF[nf], acc[mf][nf], 0, 0, 0);
    }

    // epilogue: bias + relu; C/D layout: col=lane&15, row=(lane>>4)*4+reg
    int fc = lane & 15, frow = (lane >> 4) * 4;
    #pragma unroll
    for (int nf = 0; nf < 4; ++nf) {
        int c = col0 + wn * 64 + nf * 16 + fc;
        float bc = bias[c];
        #pragma unroll
        for (int mf = 0; mf < 4; ++mf) {
            #pragma unroll
            for (int q = 0; q < 4; ++q) {
                int r = row0 + wm * 64 + mf * 16 + frow + q;
                if (r < N_NODES) {
                    float h = acc[mf][nf][q] + bc;
                    H[(size_t)r * D + c] = h > 0.f ? h : 0.f;
                }
            }
        }
    }
}

// ---------------- edge diffs -> scatter-mean -> tanh ----------------
// one wave per node, lane owns 4 dims (float4)
__global__ void k_out(const float* __restrict__ H,
                      const int* __restrict__ offsets,
                      const int* __restrict__ csr_col,
                      float* __restrict__ out) {
    int node = blockIdx.x * 4 + (threadIdx.x >> 6);
    int lane = threadIdx.x & 63;
    if (node >= N_NODES) return;
    float4 hi = *(const float4*)(H + (size_t)node * D + lane * 4);
    int st = offsets[node], en = offsets[node + 1];
    float ax = 0.f, ay = 0.f, az = 0.f, aw = 0.f;
    for (int e = st; e < en; ++e) {
        int j = csr_col[e];
        float4 hj = *(const float4*)(H + (size_t)j * D + lane * 4);
        float dx = hi.x - hj.x, dy = hi.y - hj.y, dz = hi.z - hj.z, dw = hi.w - hj.w;
        ax += dx * dx; ay += dy * dy; az += dz * dz; aw += dw * dw;
    }
    float inv = 1.f / (float)((en - st) > 1 ? (en - st) : 1);
    float4 o;
    o.x = tanhf(ax * inv); o.y = tanhf(ay * inv);
    o.z = tanhf(az * inv); o.w = tanhf(aw * inv);
    *(float4*)(out + (size_t)node * D + lane * 4) = o;
}

// ---------------- launch ----------------

extern "C" void kernel_launch(void* const* d_in, const int* in_sizes, int n_in,
                              void* d_out, int out_size, void* d_ws, size_t ws_size,
                              hipStream_t stream) {
    const float* X    = (const float*)d_in[0];
    const int*   edge = (const int*)d_in[1];
    const float* Wr   = (const float*)d_in[2];
    const float* Wn   = (const float*)d_in[3];
    const float* bias = (const float*)d_in[4];
    float* out = (float*)d_out;

    char* ws = (char*)d_ws;
    size_t off = 0;
    auto alloc = [&](size_t bytes) -> void* {
        void* p = ws + off;
        off += (bytes + 255) & ~(size_t)255;
        return p;
    };
    int*      deg     = (int*)alloc(sizeof(int) * N_NODES);
    int*      cursor  = (int*)alloc(sizeof(int) * N_NODES);
    int*      offsets = (int*)alloc(sizeof(int) * (N_NODES + 1));
    int*      csr_col = (int*)alloc(sizeof(int) * N_EDGES);
    ushort_t* A       = (ushort_t*)alloc(sizeof(ushort_t) * (size_t)N_NODES * KDIM);
    ushort_t* Wb      = (ushort_t*)alloc(sizeof(ushort_t) * (size_t)D * KDIM);
    float*    H       = (float*)alloc(sizeof(float) * (size_t)N_NODES * D);

    const int* row = edge;
    const int* col = edge + N_EDGES;

    k_zero<<<(N_NODES + 255) / 256, 256, 0, stream>>>(deg, cursor, N_NODES);
    k_deg<<<(N_EDGES + 255) / 256, 256, 0, stream>>>(row, deg, N_EDGES);
    k_scan<<<1, 1024, 0, stream>>>(deg, offsets);
    k_fill<<<(N_EDGES + 255) / 256, 256, 0, stream>>>(row, col, offsets, cursor,
                                                      csr_col, N_EDGES);
    k_castX<<<2500, 256, 0, stream>>>(X, A);
    dim3 wgrid(KDIM / 32, D / 32);
    k_prepW<<<wgrid, 256, 0, stream>>>(Wr, Wn, Wb);
    k_neigh_mean<<<2500, 256, 0, stream>>>(X, offsets, csr_col, A);

    dim3 ggrid((N_NODES + BM - 1) / BM, D / BN);
    k_gemm<<<ggrid, 256, 0, stream>>>(A, Wb, bias, H);

    k_out<<<2500, 256, 0, stream>>>(H, offsets, csr_col, out);
}

// Round 3
// 93.194 us; speedup vs baseline: 1.7798x; 1.3320x over previous
//
#include <hip/hip_runtime.h>
#include <math.h>

#define N_NODES 10000
#define N_EDGES 160000
#define D 256
#define KDIM 512   // 2*D

typedef short bf16x8 __attribute__((ext_vector_type(8)));
typedef float f32x4 __attribute__((ext_vector_type(4)));
typedef unsigned short ushort_t;

__device__ __forceinline__ ushort_t f2bf(float f) {
    unsigned u = __builtin_bit_cast(unsigned, f);
    unsigned r = (u + 0x7fffu + ((u >> 16) & 1u)) >> 16;
    return (ushort_t)r;
}
__device__ __forceinline__ float bf2f(ushort_t u) {
    unsigned v = ((unsigned)u) << 16;
    return __builtin_bit_cast(float, v);
}

// ---------------- CSR scan + fill ----------------

__global__ void k_scan(const int* __restrict__ deg, int* __restrict__ offsets) {
    __shared__ int partial[1024];
    const int n = N_NODES;
    int tid = threadIdx.x;
    const int chunk = (n + 1023) / 1024;
    int start = tid * chunk; if (start > n) start = n;
    int end = start + chunk; if (end > n) end = n;
    int s = 0;
    for (int i = start; i < end; ++i) s += deg[i];
    partial[tid] = s;
    __syncthreads();
    for (int off = 1; off < 1024; off <<= 1) {
        int v = (tid >= off) ? partial[tid - off] : 0;
        __syncthreads();
        partial[tid] += v;
        __syncthreads();
    }
    int base = (tid == 0) ? 0 : partial[tid - 1];
    for (int i = start; i < end; ++i) { offsets[i] = base; base += deg[i]; }
    if (tid == 1023) offsets[n] = partial[1023];
}

__global__ void k_fill(const int* __restrict__ row, const int* __restrict__ col,
                       const int* __restrict__ offsets, int* __restrict__ cursor,
                       int* __restrict__ csr_col, int e) {
    int i = blockIdx.x * blockDim.x + threadIdx.x;
    if (i < e) {
        int r = row[i];
        int p = atomicAdd(&cursor[r], 1);
        csr_col[offsets[r] + p] = col[i];
    }
}

// ---------------- fused prep: deg atomics | W transpose+cast | X cast ----------------
// block ranges: [0,625) deg, [625,753) prepW, [753,3253) castX
#define DEG_BLOCKS 625
#define PREPW_BLOCKS 128   // 16 k-tiles x 8 n-tiles
#define CASTX_BLOCKS 2500

__global__ void k_prep(const int* __restrict__ row, int* __restrict__ deg,
                       const float* __restrict__ Wr, const float* __restrict__ Wn,
                       ushort_t* __restrict__ Wb,
                       const float* __restrict__ X, ushort_t* __restrict__ A) {
    __shared__ float tile[32][33];
    int b = blockIdx.x;
    int t = threadIdx.x;
    if (b < DEG_BLOCKS) {
        int i = b * 256 + t;
        if (i < N_EDGES) atomicAdd(&deg[row[i]], 1);
    } else if (b < DEG_BLOCKS + PREPW_BLOCKS) {
        int wb = b - DEG_BLOCKS;
        int k0 = (wb & 15) * 32, n0 = (wb >> 4) * 32;
        {
            int r = t >> 3, c4 = t & 7;
            int k = k0 + r;
            const float* src = (k < D) ? (Wr + (size_t)k * D + n0 + c4 * 4)
                                       : (Wn + (size_t)(k - D) * D + n0 + c4 * 4);
            float4 v = *(const float4*)src;
            tile[r][c4 * 4 + 0] = v.x; tile[r][c4 * 4 + 1] = v.y;
            tile[r][c4 * 4 + 2] = v.z; tile[r][c4 * 4 + 3] = v.w;
        }
        __syncthreads();
        {
            int n = t >> 3, kq = t & 7;
            ushort4 o = make_ushort4(f2bf(tile[kq * 4 + 0][n]), f2bf(tile[kq * 4 + 1][n]),
                                     f2bf(tile[kq * 4 + 2][n]), f2bf(tile[kq * 4 + 3][n]));
            *(ushort4*)(Wb + (size_t)(n0 + n) * KDIM + k0 + kq * 4) = o;
        }
    } else {
        int nb = b - DEG_BLOCKS - PREPW_BLOCKS;
        int node = nb * 4 + (t >> 6), lane = t & 63;
        if (node < N_NODES) {
            float4 v = *(const float4*)(X + (size_t)node * D + lane * 4);
            ushort4 o = make_ushort4(f2bf(v.x), f2bf(v.y), f2bf(v.z), f2bf(v.w));
            *(ushort4*)(A + (size_t)node * KDIM + lane * 4) = o;
        }
    }
}

// ---------------- neighbor mean (bf16 gather) -> A[:, 256:512] ----------------
// one wave per node, lane owns 4 dims; reads bf16 X-half of A
__global__ void k_mean(const int* __restrict__ offsets,
                       const int* __restrict__ csr_col,
                       ushort_t* __restrict__ A) {
    int node = blockIdx.x * 4 + (threadIdx.x >> 6);
    int lane = threadIdx.x & 63;
    if (node >= N_NODES) return;
    int st = offsets[node], en = offsets[node + 1];
    float ax = 0.f, ay = 0.f, az = 0.f, aw = 0.f;
    int e = st;
    for (; e + 4 <= en; e += 4) {
        int j0 = csr_col[e], j1 = csr_col[e + 1], j2 = csr_col[e + 2], j3 = csr_col[e + 3];
        ushort4 v0 = *(const ushort4*)(A + (size_t)j0 * KDIM + lane * 4);
        ushort4 v1 = *(const ushort4*)(A + (size_t)j1 * KDIM + lane * 4);
        ushort4 v2 = *(const ushort4*)(A + (size_t)j2 * KDIM + lane * 4);
        ushort4 v3 = *(const ushort4*)(A + (size_t)j3 * KDIM + lane * 4);
        ax += bf2f(v0.x) + bf2f(v1.x) + bf2f(v2.x) + bf2f(v3.x);
        ay += bf2f(v0.y) + bf2f(v1.y) + bf2f(v2.y) + bf2f(v3.y);
        az += bf2f(v0.z) + bf2f(v1.z) + bf2f(v2.z) + bf2f(v3.z);
        aw += bf2f(v0.w) + bf2f(v1.w) + bf2f(v2.w) + bf2f(v3.w);
    }
    for (; e < en; ++e) {
        int j = csr_col[e];
        ushort4 v = *(const ushort4*)(A + (size_t)j * KDIM + lane * 4);
        ax += bf2f(v.x); ay += bf2f(v.y); az += bf2f(v.z); aw += bf2f(v.w);
    }
    float inv = 1.f / (float)((en - st) > 1 ? (en - st) : 1);
    ushort4 o = make_ushort4(f2bf(ax * inv), f2bf(ay * inv), f2bf(az * inv), f2bf(aw * inv));
    *(ushort4*)(A + (size_t)node * KDIM + D + lane * 4) = o;
}

// ---------------- MFMA GEMM: H(bf16) = relu(A @ Wb^T + b) ----------------
#define BM 128
#define BN 128
#define BK 32
#define LDK 40   // padded LDS k-stride (ushorts)

__global__ __launch_bounds__(256) void k_gemm(
    const ushort_t* __restrict__ A, const ushort_t* __restrict__ Wb,
    const float* __restrict__ bias, ushort_t* __restrict__ H) {
    __shared__ ushort_t As[BM][LDK];
    __shared__ ushort_t Bs[BN][LDK];

    int tid = threadIdx.x;
    int lane = tid & 63;
    int wave = tid >> 6;
    int wm = wave >> 1;
    int wn = wave & 1;
    int row0 = blockIdx.x * BM;
    int col0 = blockIdx.y * BN;

    f32x4 acc[4][4];
    #pragma unroll
    for (int i = 0; i < 4; ++i)
        #pragma unroll
        for (int j = 0; j < 4; ++j)
            acc[i][j] = (f32x4){0.f, 0.f, 0.f, 0.f};

    int r_a = tid >> 2;
    int kq = tid & 3;

    for (int kk = 0; kk < KDIM; kk += BK) {
        int ga0 = row0 + r_a;      if (ga0 >= N_NODES) ga0 = N_NODES - 1;
        int ga1 = row0 + r_a + 64; if (ga1 >= N_NODES) ga1 = N_NODES - 1;
        ushort4 a0 = *(const ushort4*)(A + (size_t)ga0 * KDIM + kk + kq * 8);
        ushort4 a1 = *(const ushort4*)(A + (size_t)ga0 * KDIM + kk + kq * 8 + 4);
        ushort4 a2 = *(const ushort4*)(A + (size_t)ga1 * KDIM + kk + kq * 8);
        ushort4 a3 = *(const ushort4*)(A + (size_t)ga1 * KDIM + kk + kq * 8 + 4);
        ushort4 b0 = *(const ushort4*)(Wb + (size_t)(col0 + r_a) * KDIM + kk + kq * 8);
        ushort4 b1 = *(const ushort4*)(Wb + (size_t)(col0 + r_a) * KDIM + kk + kq * 8 + 4);
        ushort4 b2 = *(const ushort4*)(Wb + (size_t)(col0 + r_a + 64) * KDIM + kk + kq * 8);
        ushort4 b3 = *(const ushort4*)(Wb + (size_t)(col0 + r_a + 64) * KDIM + kk + kq * 8 + 4);

        __syncthreads();
        *(ushort4*)&As[r_a][kq * 8]          = a0;
        *(ushort4*)&As[r_a][kq * 8 + 4]      = a1;
        *(ushort4*)&As[r_a + 64][kq * 8]     = a2;
        *(ushort4*)&As[r_a + 64][kq * 8 + 4] = a3;
        *(ushort4*)&Bs[r_a][kq * 8]          = b0;
        *(ushort4*)&Bs[r_a][kq * 8 + 4]      = b1;
        *(ushort4*)&Bs[r_a + 64][kq * 8]     = b2;
        *(ushort4*)&Bs[r_a + 64][kq * 8 + 4] = b3;
        __syncthreads();

        int fr = lane & 15, fg = (lane >> 4) * 8;
        bf16x8 aF[4], bF[4];
        #pragma unroll
        for (int mf = 0; mf < 4; ++mf)
            aF[mf] = *(const bf16x8*)&As[wm * 64 + mf * 16 + fr][fg];
        #pragma unroll
        for (int nf = 0; nf < 4; ++nf)
            bF[nf] = *(const bf16x8*)&Bs[wn * 64 + nf * 16 + fr][fg];
        #pragma unroll
        for (int mf = 0; mf < 4; ++mf)
            #pragma unroll
            for (int nf = 0; nf < 4; ++nf)
                acc[mf][nf] = __builtin_amdgcn_mfma_f32_16x16x32_bf16(
                    aF[mf], bF[nf], acc[mf][nf], 0, 0, 0);
    }

    int fc = lane & 15, frow = (lane >> 4) * 4;
    #pragma unroll
    for (int nf = 0; nf < 4; ++nf) {
        int c = col0 + wn * 64 + nf * 16 + fc;
        float bc = bias[c];
        #pragma unroll
        for (int mf = 0; mf < 4; ++mf) {
            #pragma unroll
            for (int q = 0; q < 4; ++q) {
                int r = row0 + wm * 64 + mf * 16 + frow + q;
                if (r < N_NODES) {
                    float h = acc[mf][nf][q] + bc;
                    H[(size_t)r * D + c] = f2bf(h > 0.f ? h : 0.f);
                }
            }
        }
    }
}

// ---------------- edge diffs (bf16 gather) -> scatter-mean -> tanh ----------------
__global__ void k_out(const ushort_t* __restrict__ H,
                      const int* __restrict__ offsets,
                      const int* __restrict__ csr_col,
                      float* __restrict__ out) {
    int node = blockIdx.x * 4 + (threadIdx.x >> 6);
    int lane = threadIdx.x & 63;
    if (node >= N_NODES) return;
    ushort4 hb = *(const ushort4*)(H + (size_t)node * D + lane * 4);
    float hx = bf2f(hb.x), hy = bf2f(hb.y), hz = bf2f(hb.z), hw = bf2f(hb.w);
    int st = offsets[node], en = offsets[node + 1];
    float ax = 0.f, ay = 0.f, az = 0.f, aw = 0.f;
    int e = st;
    for (; e + 4 <= en; e += 4) {
        int j0 = csr_col[e], j1 = csr_col[e + 1], j2 = csr_col[e + 2], j3 = csr_col[e + 3];
        ushort4 v0 = *(const ushort4*)(H + (size_t)j0 * D + lane * 4);
        ushort4 v1 = *(const ushort4*)(H + (size_t)j1 * D + lane * 4);
        ushort4 v2 = *(const ushort4*)(H + (size_t)j2 * D + lane * 4);
        ushort4 v3 = *(const ushort4*)(H + (size_t)j3 * D + lane * 4);
        float d;
        d = hx - bf2f(v0.x); ax += d * d;  d = hy - bf2f(v0.y); ay += d * d;
        d = hz - bf2f(v0.z); az += d * d;  d = hw - bf2f(v0.w); aw += d * d;
        d = hx - bf2f(v1.x); ax += d * d;  d = hy - bf2f(v1.y); ay += d * d;
        d = hz - bf2f(v1.z); az += d * d;  d = hw - bf2f(v1.w); aw += d * d;
        d = hx - bf2f(v2.x); ax += d * d;  d = hy - bf2f(v2.y); ay += d * d;
        d = hz - bf2f(v2.z); az += d * d;  d = hw - bf2f(v2.w); aw += d * d;
        d = hx - bf2f(v3.x); ax += d * d;  d = hy - bf2f(v3.y); ay += d * d;
        d = hz - bf2f(v3.z); az += d * d;  d = hw - bf2f(v3.w); aw += d * d;
    }
    for (; e < en; ++e) {
        int j = csr_col[e];
        ushort4 v = *(const ushort4*)(H + (size_t)j * D + lane * 4);
        float d;
        d = hx - bf2f(v.x); ax += d * d;  d = hy - bf2f(v.y); ay += d * d;
        d = hz - bf2f(v.z); az += d * d;  d = hw - bf2f(v.w); aw += d * d;
    }
    float inv = 1.f / (float)((en - st) > 1 ? (en - st) : 1);
    float4 o;
    o.x = tanhf(ax * inv); o.y = tanhf(ay * inv);
    o.z = tanhf(az * inv); o.w = tanhf(aw * inv);
    *(float4*)(out + (size_t)node * D + lane * 4) = o;
}

// ---------------- launch ----------------

extern "C" void kernel_launch(void* const* d_in, const int* in_sizes, int n_in,
                              void* d_out, int out_size, void* d_ws, size_t ws_size,
                              hipStream_t stream) {
    const float* X    = (const float*)d_in[0];
    const int*   edge = (const int*)d_in[1];
    const float* Wr   = (const float*)d_in[2];
    const float* Wn   = (const float*)d_in[3];
    const float* bias = (const float*)d_in[4];
    float* out = (float*)d_out;

    char* ws = (char*)d_ws;
    size_t off = 0;
    auto alloc = [&](size_t bytes) -> void* {
        void* p = ws + off;
        off += (bytes + 255) & ~(size_t)255;
        return p;
    };
    int*      degcur  = (int*)alloc(sizeof(int) * 2 * N_NODES);   // deg | cursor
    int*      offsets = (int*)alloc(sizeof(int) * (N_NODES + 1));
    int*      csr_col = (int*)alloc(sizeof(int) * N_EDGES);
    ushort_t* A       = (ushort_t*)alloc(sizeof(ushort_t) * (size_t)N_NODES * KDIM);
    ushort_t* Wb      = (ushort_t*)alloc(sizeof(ushort_t) * (size_t)D * KDIM);
    ushort_t* H       = (ushort_t*)alloc(sizeof(ushort_t) * (size_t)N_NODES * D);

    int* deg    = degcur;
    int* cursor = degcur + N_NODES;
    const int* row = edge;
    const int* col = edge + N_EDGES;

    hipMemsetAsync(degcur, 0, sizeof(int) * 2 * N_NODES, stream);
    k_prep<<<DEG_BLOCKS + PREPW_BLOCKS + CASTX_BLOCKS, 256, 0, stream>>>(
        row, deg, Wr, Wn, Wb, X, A);
    k_scan<<<1, 1024, 0, stream>>>(deg, offsets);
    k_fill<<<(N_EDGES + 255) / 256, 256, 0, stream>>>(row, col, offsets, cursor,
                                                      csr_col, N_EDGES);
    k_mean<<<2500, 256, 0, stream>>>(offsets, csr_col, A);

    dim3 ggrid((N_NODES + BM - 1) / BM, D / BN);
    k_gemm<<<ggrid, 256, 0, stream>>>(A, Wb, bias, H);

    k_out<<<2500, 256, 0, stream>>>(H, offsets, csr_col, out);
}

// Round 4
// 92.626 us; speedup vs baseline: 1.7907x; 1.0061x over previous
//
#include <hip/hip_runtime.h>
#include <math.h>

#define N_NODES 10000
#define N_EDGES 160000
#define D 256
#define KDIM 512   // 2*D

typedef short bf16x8 __attribute__((ext_vector_type(8)));
typedef float f32x4 __attribute__((ext_vector_type(4)));
typedef unsigned short ushort_t;

__device__ __forceinline__ ushort_t f2bf(float f) {
    unsigned u = __builtin_bit_cast(unsigned, f);
    unsigned r = (u + 0x7fffu + ((u >> 16) & 1u)) >> 16;
    return (ushort_t)r;
}
__device__ __forceinline__ float bf2f(ushort_t u) {
    unsigned v = ((unsigned)u) << 16;
    return __builtin_bit_cast(float, v);
}

// ---------------- zero (replaces hipMemsetAsync: graph memset node cost ~44us) ----------------

__global__ void k_zero(int* __restrict__ p, int n) {
    int i = blockIdx.x * blockDim.x + threadIdx.x;
    if (i < n) p[i] = 0;
}

// ---------------- CSR scan + fill ----------------

__global__ void k_scan(const int* __restrict__ deg, int* __restrict__ offsets) {
    __shared__ int partial[1024];
    const int n = N_NODES;
    int tid = threadIdx.x;
    const int chunk = (n + 1023) / 1024;
    int start = tid * chunk; if (start > n) start = n;
    int end = start + chunk; if (end > n) end = n;
    int s = 0;
    for (int i = start; i < end; ++i) s += deg[i];
    partial[tid] = s;
    __syncthreads();
    for (int off = 1; off < 1024; off <<= 1) {
        int v = (tid >= off) ? partial[tid - off] : 0;
        __syncthreads();
        partial[tid] += v;
        __syncthreads();
    }
    int base = (tid == 0) ? 0 : partial[tid - 1];
    for (int i = start; i < end; ++i) { offsets[i] = base; base += deg[i]; }
    if (tid == 1023) offsets[n] = partial[1023];
}

__global__ void k_fill(const int* __restrict__ row, const int* __restrict__ col,
                       const int* __restrict__ offsets, int* __restrict__ cursor,
                       int* __restrict__ csr_col, int e) {
    int i = blockIdx.x * blockDim.x + threadIdx.x;
    if (i < e) {
        int r = row[i];
        int p = atomicAdd(&cursor[r], 1);
        csr_col[offsets[r] + p] = col[i];
    }
}

// ---------------- fused prep: deg atomics | W transpose+cast | X cast ----------------
#define DEG_BLOCKS 625
#define PREPW_BLOCKS 128   // 16 k-tiles x 8 n-tiles
#define CASTX_BLOCKS 2500

__global__ void k_prep(const int* __restrict__ row, int* __restrict__ deg,
                       const float* __restrict__ Wr, const float* __restrict__ Wn,
                       ushort_t* __restrict__ Wb,
                       const float* __restrict__ X, ushort_t* __restrict__ A) {
    __shared__ float tile[32][33];
    int b = blockIdx.x;
    int t = threadIdx.x;
    if (b < DEG_BLOCKS) {
        int i = b * 256 + t;
        if (i < N_EDGES) atomicAdd(&deg[row[i]], 1);
    } else if (b < DEG_BLOCKS + PREPW_BLOCKS) {
        int wb = b - DEG_BLOCKS;
        int k0 = (wb & 15) * 32, n0 = (wb >> 4) * 32;
        {
            int r = t >> 3, c4 = t & 7;
            int k = k0 + r;
            const float* src = (k < D) ? (Wr + (size_t)k * D + n0 + c4 * 4)
                                       : (Wn + (size_t)(k - D) * D + n0 + c4 * 4);
            float4 v = *(const float4*)src;
            tile[r][c4 * 4 + 0] = v.x; tile[r][c4 * 4 + 1] = v.y;
            tile[r][c4 * 4 + 2] = v.z; tile[r][c4 * 4 + 3] = v.w;
        }
        __syncthreads();
        {
            int n = t >> 3, kq = t & 7;
            ushort4 o = make_ushort4(f2bf(tile[kq * 4 + 0][n]), f2bf(tile[kq * 4 + 1][n]),
                                     f2bf(tile[kq * 4 + 2][n]), f2bf(tile[kq * 4 + 3][n]));
            *(ushort4*)(Wb + (size_t)(n0 + n) * KDIM + k0 + kq * 4) = o;
        }
    } else {
        int nb = b - DEG_BLOCKS - PREPW_BLOCKS;
        int node = nb * 4 + (t >> 6), lane = t & 63;
        if (node < N_NODES) {
            float4 v = *(const float4*)(X + (size_t)node * D + lane * 4);
            ushort4 o = make_ushort4(f2bf(v.x), f2bf(v.y), f2bf(v.z), f2bf(v.w));
            *(ushort4*)(A + (size_t)node * KDIM + lane * 4) = o;
        }
    }
}

// ---------------- neighbor mean (bf16 gather) -> A[:, 256:512] ----------------

__global__ void k_mean(const int* __restrict__ offsets,
                       const int* __restrict__ csr_col,
                       ushort_t* __restrict__ A) {
    int node = blockIdx.x * 4 + (threadIdx.x >> 6);
    int lane = threadIdx.x & 63;
    if (node >= N_NODES) return;
    int st = offsets[node], en = offsets[node + 1];
    float ax = 0.f, ay = 0.f, az = 0.f, aw = 0.f;
    int e = st;
    for (; e + 4 <= en; e += 4) {
        int j0 = csr_col[e], j1 = csr_col[e + 1], j2 = csr_col[e + 2], j3 = csr_col[e + 3];
        ushort4 v0 = *(const ushort4*)(A + (size_t)j0 * KDIM + lane * 4);
        ushort4 v1 = *(const ushort4*)(A + (size_t)j1 * KDIM + lane * 4);
        ushort4 v2 = *(const ushort4*)(A + (size_t)j2 * KDIM + lane * 4);
        ushort4 v3 = *(const ushort4*)(A + (size_t)j3 * KDIM + lane * 4);
        ax += bf2f(v0.x) + bf2f(v1.x) + bf2f(v2.x) + bf2f(v3.x);
        ay += bf2f(v0.y) + bf2f(v1.y) + bf2f(v2.y) + bf2f(v3.y);
        az += bf2f(v0.z) + bf2f(v1.z) + bf2f(v2.z) + bf2f(v3.z);
        aw += bf2f(v0.w) + bf2f(v1.w) + bf2f(v2.w) + bf2f(v3.w);
    }
    for (; e < en; ++e) {
        int j = csr_col[e];
        ushort4 v = *(const ushort4*)(A + (size_t)j * KDIM + lane * 4);
        ax += bf2f(v.x); ay += bf2f(v.y); az += bf2f(v.z); aw += bf2f(v.w);
    }
    float inv = 1.f / (float)((en - st) > 1 ? (en - st) : 1);
    ushort4 o = make_ushort4(f2bf(ax * inv), f2bf(ay * inv), f2bf(az * inv), f2bf(aw * inv));
    *(ushort4*)(A + (size_t)node * KDIM + D + lane * 4) = o;
}

// ---------------- MFMA GEMM: H(bf16) = relu(A @ Wb^T + b) ----------------
#define BM 128
#define BN 128
#define BK 32
#define LDK 40   // padded LDS k-stride (ushorts)

__global__ __launch_bounds__(256) void k_gemm(
    const ushort_t* __restrict__ A, const ushort_t* __restrict__ Wb,
    const float* __restrict__ bias, ushort_t* __restrict__ H) {
    __shared__ ushort_t As[BM][LDK];
    __shared__ ushort_t Bs[BN][LDK];

    int tid = threadIdx.x;
    int lane = tid & 63;
    int wave = tid >> 6;
    int wm = wave >> 1;
    int wn = wave & 1;
    int row0 = blockIdx.x * BM;
    int col0 = blockIdx.y * BN;

    f32x4 acc[4][4];
    #pragma unroll
    for (int i = 0; i < 4; ++i)
        #pragma unroll
        for (int j = 0; j < 4; ++j)
            acc[i][j] = (f32x4){0.f, 0.f, 0.f, 0.f};

    int r_a = tid >> 2;
    int kq = tid & 3;

    for (int kk = 0; kk < KDIM; kk += BK) {
        int ga0 = row0 + r_a;      if (ga0 >= N_NODES) ga0 = N_NODES - 1;
        int ga1 = row0 + r_a + 64; if (ga1 >= N_NODES) ga1 = N_NODES - 1;
        ushort4 a0 = *(const ushort4*)(A + (size_t)ga0 * KDIM + kk + kq * 8);
        ushort4 a1 = *(const ushort4*)(A + (size_t)ga0 * KDIM + kk + kq * 8 + 4);
        ushort4 a2 = *(const ushort4*)(A + (size_t)ga1 * KDIM + kk + kq * 8);
        ushort4 a3 = *(const ushort4*)(A + (size_t)ga1 * KDIM + kk + kq * 8 + 4);
        ushort4 b0 = *(const ushort4*)(Wb + (size_t)(col0 + r_a) * KDIM + kk + kq * 8);
        ushort4 b1 = *(const ushort4*)(Wb + (size_t)(col0 + r_a) * KDIM + kk + kq * 8 + 4);
        ushort4 b2 = *(const ushort4*)(Wb + (size_t)(col0 + r_a + 64) * KDIM + kk + kq * 8);
        ushort4 b3 = *(const ushort4*)(Wb + (size_t)(col0 + r_a + 64) * KDIM + kk + kq * 8 + 4);

        __syncthreads();
        *(ushort4*)&As[r_a][kq * 8]          = a0;
        *(ushort4*)&As[r_a][kq * 8 + 4]      = a1;
        *(ushort4*)&As[r_a + 64][kq * 8]     = a2;
        *(ushort4*)&As[r_a + 64][kq * 8 + 4] = a3;
        *(ushort4*)&Bs[r_a][kq * 8]          = b0;
        *(ushort4*)&Bs[r_a][kq * 8 + 4]      = b1;
        *(ushort4*)&Bs[r_a + 64][kq * 8]     = b2;
        *(ushort4*)&Bs[r_a + 64][kq * 8 + 4] = b3;
        __syncthreads();

        int fr = lane & 15, fg = (lane >> 4) * 8;
        bf16x8 aF[4], bF[4];
        #pragma unroll
        for (int mf = 0; mf < 4; ++mf)
            aF[mf] = *(const bf16x8*)&As[wm * 64 + mf * 16 + fr][fg];
        #pragma unroll
        for (int nf = 0; nf < 4; ++nf)
            bF[nf] = *(const bf16x8*)&Bs[wn * 64 + nf * 16 + fr][fg];
        #pragma unroll
        for (int mf = 0; mf < 4; ++mf)
            #pragma unroll
            for (int nf = 0; nf < 4; ++nf)
                acc[mf][nf] = __builtin_amdgcn_mfma_f32_16x16x32_bf16(
                    aF[mf], bF[nf], acc[mf][nf], 0, 0, 0);
    }

    int fc = lane & 15, frow = (lane >> 4) * 4;
    #pragma unroll
    for (int nf = 0; nf < 4; ++nf) {
        int c = col0 + wn * 64 + nf * 16 + fc;
        float bc = bias[c];
        #pragma unroll
        for (int mf = 0; mf < 4; ++mf) {
            #pragma unroll
            for (int q = 0; q < 4; ++q) {
                int r = row0 + wm * 64 + mf * 16 + frow + q;
                if (r < N_NODES) {
                    float h = acc[mf][nf][q] + bc;
                    H[(size_t)r * D + c] = f2bf(h > 0.f ? h : 0.f);
                }
            }
        }
    }
}

// ---------------- edge diffs (bf16 gather) -> scatter-mean -> tanh ----------------
__global__ void k_out(const ushort_t* __restrict__ H,
                      const int* __restrict__ offsets,
                      const int* __restrict__ csr_col,
                      float* __restrict__ out) {
    int node = blockIdx.x * 4 + (threadIdx.x >> 6);
    int lane = threadIdx.x & 63;
    if (node >= N_NODES) return;
    ushort4 hb = *(const ushort4*)(H + (size_t)node * D + lane * 4);
    float hx = bf2f(hb.x), hy = bf2f(hb.y), hz = bf2f(hb.z), hw = bf2f(hb.w);
    int st = offsets[node], en = offsets[node + 1];
    float ax = 0.f, ay = 0.f, az = 0.f, aw = 0.f;
    int e = st;
    for (; e + 4 <= en; e += 4) {
        int j0 = csr_col[e], j1 = csr_col[e + 1], j2 = csr_col[e + 2], j3 = csr_col[e + 3];
        ushort4 v0 = *(const ushort4*)(H + (size_t)j0 * D + lane * 4);
        ushort4 v1 = *(const ushort4*)(H + (size_t)j1 * D + lane * 4);
        ushort4 v2 = *(const ushort4*)(H + (size_t)j2 * D + lane * 4);
        ushort4 v3 = *(const ushort4*)(H + (size_t)j3 * D + lane * 4);
        float d;
        d = hx - bf2f(v0.x); ax += d * d;  d = hy - bf2f(v0.y); ay += d * d;
        d = hz - bf2f(v0.z); az += d * d;  d = hw - bf2f(v0.w); aw += d * d;
        d = hx - bf2f(v1.x); ax += d * d;  d = hy - bf2f(v1.y); ay += d * d;
        d = hz - bf2f(v1.z); az += d * d;  d = hw - bf2f(v1.w); aw += d * d;
        d = hx - bf2f(v2.x); ax += d * d;  d = hy - bf2f(v2.y); ay += d * d;
        d = hz - bf2f(v2.z); az += d * d;  d = hw - bf2f(v2.w); aw += d * d;
        d = hx - bf2f(v3.x); ax += d * d;  d = hy - bf2f(v3.y); ay += d * d;
        d = hz - bf2f(v3.z); az += d * d;  d = hw - bf2f(v3.w); aw += d * d;
    }
    for (; e < en; ++e) {
        int j = csr_col[e];
        ushort4 v = *(const ushort4*)(H + (size_t)j * D + lane * 4);
        float d;
        d = hx - bf2f(v.x); ax += d * d;  d = hy - bf2f(v.y); ay += d * d;
        d = hz - bf2f(v.z); az += d * d;  d = hw - bf2f(v.w); aw += d * d;
    }
    float inv = 1.f / (float)((en - st) > 1 ? (en - st) : 1);
    float4 o;
    o.x = tanhf(ax * inv); o.y = tanhf(ay * inv);
    o.z = tanhf(az * inv); o.w = tanhf(aw * inv);
    *(float4*)(out + (size_t)node * D + lane * 4) = o;
}

// ---------------- launch ----------------

extern "C" void kernel_launch(void* const* d_in, const int* in_sizes, int n_in,
                              void* d_out, int out_size, void* d_ws, size_t ws_size,
                              hipStream_t stream) {
    const float* X    = (const float*)d_in[0];
    const int*   edge = (const int*)d_in[1];
    const float* Wr   = (const float*)d_in[2];
    const float* Wn   = (const float*)d_in[3];
    const float* bias = (const float*)d_in[4];
    float* out = (float*)d_out;

    char* ws = (char*)d_ws;
    size_t off = 0;
    auto alloc = [&](size_t bytes) -> void* {
        void* p = ws + off;
        off += (bytes + 255) & ~(size_t)255;
        return p;
    };
    int*      degcur  = (int*)alloc(sizeof(int) * 2 * N_NODES);   // deg | cursor
    int*      offsets = (int*)alloc(sizeof(int) * (N_NODES + 1));
    int*      csr_col = (int*)alloc(sizeof(int) * N_EDGES);
    ushort_t* A       = (ushort_t*)alloc(sizeof(ushort_t) * (size_t)N_NODES * KDIM);
    ushort_t* Wb      = (ushort_t*)alloc(sizeof(ushort_t) * (size_t)D * KDIM);
    ushort_t* H       = (ushort_t*)alloc(sizeof(ushort_t) * (size_t)N_NODES * D);

    int* deg    = degcur;
    int* cursor = degcur + N_NODES;
    const int* row = edge;
    const int* col = edge + N_EDGES;

    k_zero<<<(2 * N_NODES + 255) / 256, 256, 0, stream>>>(degcur, 2 * N_NODES);
    k_prep<<<DEG_BLOCKS + PREPW_BLOCKS + CASTX_BLOCKS, 256, 0, stream>>>(
        row, deg, Wr, Wn, Wb, X, A);
    k_scan<<<1, 1024, 0, stream>>>(deg, offsets);
    k_fill<<<(N_EDGES + 255) / 256, 256, 0, stream>>>(row, col, offsets, cursor,
                                                      csr_col, N_EDGES);
    k_mean<<<2500, 256, 0, stream>>>(offsets, csr_col, A);

    dim3 ggrid((N_NODES + BM - 1) / BM, D / BN);
    k_gemm<<<ggrid, 256, 0, stream>>>(A, Wb, bias, H);

    k_out<<<2500, 256, 0, stream>>>(H, offsets, csr_col, out);
}

// Round 5
// 86.915 us; speedup vs baseline: 1.9084x; 1.0657x over previous
//
#include <hip/hip_runtime.h>
#include <math.h>

#define N_NODES 10000
#define N_EDGES 160000
#define D 256
#define KDIM 512   // 2*D
#define SPLIT 5000 // col partition for L2-resident two-sweep gathers

typedef short bf16x8 __attribute__((ext_vector_type(8)));
typedef float f32x4 __attribute__((ext_vector_type(4)));
typedef unsigned short ushort_t;

__device__ __forceinline__ ushort_t f2bf(float f) {
    unsigned u = __builtin_bit_cast(unsigned, f);
    unsigned r = (u + 0x7fffu + ((u >> 16) & 1u)) >> 16;
    return (ushort_t)r;
}
__device__ __forceinline__ float bf2f(ushort_t u) {
    unsigned v = ((unsigned)u) << 16;
    return __builtin_bit_cast(float, v);
}

// ---------------- zero ----------------

__global__ void k_zero(int* __restrict__ p, int n) {
    int i = blockIdx.x * blockDim.x + threadIdx.x;
    if (i < n) p[i] = 0;
}

// ---------------- CSR scan + fill ----------------

__global__ void k_scan(const int* __restrict__ deg, int* __restrict__ offsets) {
    __shared__ int partial[1024];
    const int n = N_NODES;
    int tid = threadIdx.x;
    const int chunk = (n + 1023) / 1024;
    int start = tid * chunk; if (start > n) start = n;
    int end = start + chunk; if (end > n) end = n;
    int s = 0;
    for (int i = start; i < end; ++i) s += deg[i];
    partial[tid] = s;
    __syncthreads();
    for (int off = 1; off < 1024; off <<= 1) {
        int v = (tid >= off) ? partial[tid - off] : 0;
        __syncthreads();
        partial[tid] += v;
        __syncthreads();
    }
    int base = (tid == 0) ? 0 : partial[tid - 1];
    for (int i = start; i < end; ++i) { offsets[i] = base; base += deg[i]; }
    if (tid == 1023) offsets[n] = partial[1023];
}

// partition each node's segment: cols < SPLIT at the front, >= SPLIT at the back
__global__ void k_fill(const int* __restrict__ row, const int* __restrict__ col,
                       const int* __restrict__ offsets, int* __restrict__ curLo,
                       int* __restrict__ curHi, int* __restrict__ csr_col, int e) {
    int i = blockIdx.x * blockDim.x + threadIdx.x;
    if (i < e) {
        int r = row[i], c = col[i];
        if (c < SPLIT) {
            int p = atomicAdd(&curLo[r], 1);
            csr_col[offsets[r] + p] = c;
        } else {
            int p = atomicAdd(&curHi[r], 1);
            csr_col[offsets[r + 1] - 1 - p] = c;
        }
    }
}

// ---------------- fused prep: deg atomics | W transpose+cast | X cast ----------------
#define DEG_BLOCKS 625
#define PREPW_BLOCKS 128   // 16 k-tiles x 8 n-tiles
#define CASTX_BLOCKS 2500

__global__ void k_prep(const int* __restrict__ row, int* __restrict__ deg,
                       const float* __restrict__ Wr, const float* __restrict__ Wn,
                       ushort_t* __restrict__ Wb,
                       const float* __restrict__ X, ushort_t* __restrict__ A) {
    __shared__ float tile[32][33];
    int b = blockIdx.x;
    int t = threadIdx.x;
    if (b < DEG_BLOCKS) {
        int i = b * 256 + t;
        if (i < N_EDGES) atomicAdd(&deg[row[i]], 1);
    } else if (b < DEG_BLOCKS + PREPW_BLOCKS) {
        int wb = b - DEG_BLOCKS;
        int k0 = (wb & 15) * 32, n0 = (wb >> 4) * 32;
        {
            int r = t >> 3, c4 = t & 7;
            int k = k0 + r;
            const float* src = (k < D) ? (Wr + (size_t)k * D + n0 + c4 * 4)
                                       : (Wn + (size_t)(k - D) * D + n0 + c4 * 4);
            float4 v = *(const float4*)src;
            tile[r][c4 * 4 + 0] = v.x; tile[r][c4 * 4 + 1] = v.y;
            tile[r][c4 * 4 + 2] = v.z; tile[r][c4 * 4 + 3] = v.w;
        }
        __syncthreads();
        {
            int n = t >> 3, kq = t & 7;
            ushort4 o = make_ushort4(f2bf(tile[kq * 4 + 0][n]), f2bf(tile[kq * 4 + 1][n]),
                                     f2bf(tile[kq * 4 + 2][n]), f2bf(tile[kq * 4 + 3][n]));
            *(ushort4*)(Wb + (size_t)(n0 + n) * KDIM + k0 + kq * 4) = o;
        }
    } else {
        int nb = b - DEG_BLOCKS - PREPW_BLOCKS;
        int node = nb * 4 + (t >> 6), lane = t & 63;
        if (node < N_NODES) {
            float4 v = *(const float4*)(X + (size_t)node * D + lane * 4);
            ushort4 o = make_ushort4(f2bf(v.x), f2bf(v.y), f2bf(v.z), f2bf(v.w));
            *(ushort4*)(A + (size_t)node * KDIM + lane * 4) = o;
        }
    }
}

// ---------------- neighbor mean (two-sweep bf16 gather) -> A[:, 256:512] ----------------

__global__ void k_mean(const int* __restrict__ offsets, const int* __restrict__ nlo,
                       const int* __restrict__ csr_col, ushort_t* __restrict__ A) {
    int node = blockIdx.x * 4 + (threadIdx.x >> 6);
    int lane = threadIdx.x & 63;
    if (node >= N_NODES) return;
    int st = offsets[node], en = offsets[node + 1];
    int mid = st + nlo[node];
    float ax = 0.f, ay = 0.f, az = 0.f, aw = 0.f;
    #pragma unroll 1
    for (int half = 0; half < 2; ++half) {
        int s = half ? mid : st;
        int t = half ? en : mid;
        int e = s;
        for (; e + 4 <= t; e += 4) {
            int j0 = csr_col[e], j1 = csr_col[e + 1], j2 = csr_col[e + 2], j3 = csr_col[e + 3];
            ushort4 v0 = *(const ushort4*)(A + (size_t)j0 * KDIM + lane * 4);
            ushort4 v1 = *(const ushort4*)(A + (size_t)j1 * KDIM + lane * 4);
            ushort4 v2 = *(const ushort4*)(A + (size_t)j2 * KDIM + lane * 4);
            ushort4 v3 = *(const ushort4*)(A + (size_t)j3 * KDIM + lane * 4);
            ax += bf2f(v0.x) + bf2f(v1.x) + bf2f(v2.x) + bf2f(v3.x);
            ay += bf2f(v0.y) + bf2f(v1.y) + bf2f(v2.y) + bf2f(v3.y);
            az += bf2f(v0.z) + bf2f(v1.z) + bf2f(v2.z) + bf2f(v3.z);
            aw += bf2f(v0.w) + bf2f(v1.w) + bf2f(v2.w) + bf2f(v3.w);
        }
        for (; e < t; ++e) {
            int j = csr_col[e];
            ushort4 v = *(const ushort4*)(A + (size_t)j * KDIM + lane * 4);
            ax += bf2f(v.x); ay += bf2f(v.y); az += bf2f(v.z); aw += bf2f(v.w);
        }
    }
    float inv = 1.f / (float)((en - st) > 1 ? (en - st) : 1);
    ushort4 o = make_ushort4(f2bf(ax * inv), f2bf(ay * inv), f2bf(az * inv), f2bf(aw * inv));
    *(ushort4*)(A + (size_t)node * KDIM + D + lane * 4) = o;
}

// ---------------- MFMA GEMM: H(bf16) = relu(A @ Wb^T + b) ----------------
// BM=64 -> 157x2 = 314 blocks: cover all 256 CUs (was 158)
#define BM 64
#define BN 128
#define BK 32
#define LDK 40   // padded LDS k-stride (ushorts)

__global__ __launch_bounds__(256) void k_gemm(
    const ushort_t* __restrict__ A, const ushort_t* __restrict__ Wb,
    const float* __restrict__ bias, ushort_t* __restrict__ H) {
    __shared__ ushort_t As[BM][LDK];
    __shared__ ushort_t Bs[BN][LDK];

    int tid = threadIdx.x;
    int lane = tid & 63;
    int wave = tid >> 6;
    int wm = wave >> 1;   // 0..1: 32-row half
    int wn = wave & 1;    // 0..1: 64-col half
    int row0 = blockIdx.x * BM;
    int col0 = blockIdx.y * BN;

    f32x4 acc[2][4];
    #pragma unroll
    for (int i = 0; i < 2; ++i)
        #pragma unroll
        for (int j = 0; j < 4; ++j)
            acc[i][j] = (f32x4){0.f, 0.f, 0.f, 0.f};

    int r_a = tid >> 2;
    int kq = tid & 3;

    for (int kk = 0; kk < KDIM; kk += BK) {
        int ga = row0 + r_a; if (ga >= N_NODES) ga = N_NODES - 1;
        ushort4 a0 = *(const ushort4*)(A + (size_t)ga * KDIM + kk + kq * 8);
        ushort4 a1 = *(const ushort4*)(A + (size_t)ga * KDIM + kk + kq * 8 + 4);
        ushort4 b0 = *(const ushort4*)(Wb + (size_t)(col0 + r_a) * KDIM + kk + kq * 8);
        ushort4 b1 = *(const ushort4*)(Wb + (size_t)(col0 + r_a) * KDIM + kk + kq * 8 + 4);
        ushort4 b2 = *(const ushort4*)(Wb + (size_t)(col0 + r_a + 64) * KDIM + kk + kq * 8);
        ushort4 b3 = *(const ushort4*)(Wb + (size_t)(col0 + r_a + 64) * KDIM + kk + kq * 8 + 4);

        __syncthreads();
        *(ushort4*)&As[r_a][kq * 8]          = a0;
        *(ushort4*)&As[r_a][kq * 8 + 4]      = a1;
        *(ushort4*)&Bs[r_a][kq * 8]          = b0;
        *(ushort4*)&Bs[r_a][kq * 8 + 4]      = b1;
        *(ushort4*)&Bs[r_a + 64][kq * 8]     = b2;
        *(ushort4*)&Bs[r_a + 64][kq * 8 + 4] = b3;
        __syncthreads();

        int fr = lane & 15, fg = (lane >> 4) * 8;
        bf16x8 aF[2], bF[4];
        #pragma unroll
        for (int mf = 0; mf < 2; ++mf)
            aF[mf] = *(const bf16x8*)&As[wm * 32 + mf * 16 + fr][fg];
        #pragma unroll
        for (int nf = 0; nf < 4; ++nf)
            bF[nf] = *(const bf16x8*)&Bs[wn * 64 + nf * 16 + fr][fg];
        #pragma unroll
        for (int mf = 0; mf < 2; ++mf)
            #pragma unroll
            for (int nf = 0; nf < 4; ++nf)
                acc[mf][nf] = __builtin_amdgcn_mfma_f32_16x16x32_bf16(
                    aF[mf], bF[nf], acc[mf][nf], 0, 0, 0);
    }

    int fc = lane & 15, frow = (lane >> 4) * 4;
    #pragma unroll
    for (int nf = 0; nf < 4; ++nf) {
        int c = col0 + wn * 64 + nf * 16 + fc;
        float bc = bias[c];
        #pragma unroll
        for (int mf = 0; mf < 2; ++mf) {
            #pragma unroll
            for (int q = 0; q < 4; ++q) {
                int r = row0 + wm * 32 + mf * 16 + frow + q;
                if (r < N_NODES) {
                    float h = acc[mf][nf][q] + bc;
                    H[(size_t)r * D + c] = f2bf(h > 0.f ? h : 0.f);
                }
            }
        }
    }
}

// ---------------- edge diffs (two-sweep bf16 gather) -> scatter-mean -> tanh ----------------
__global__ void k_out(const ushort_t* __restrict__ H,
                      const int* __restrict__ offsets, const int* __restrict__ nlo,
                      const int* __restrict__ csr_col,
                      float* __restrict__ out) {
    int node = blockIdx.x * 4 + (threadIdx.x >> 6);
    int lane = threadIdx.x & 63;
    if (node >= N_NODES) return;
    ushort4 hb = *(const ushort4*)(H + (size_t)node * D + lane * 4);
    float hx = bf2f(hb.x), hy = bf2f(hb.y), hz = bf2f(hb.z), hw = bf2f(hb.w);
    int st = offsets[node], en = offsets[node + 1];
    int mid = st + nlo[node];
    float ax = 0.f, ay = 0.f, az = 0.f, aw = 0.f;
    #pragma unroll 1
    for (int half = 0; half < 2; ++half) {
        int s = half ? mid : st;
        int t = half ? en : mid;
        int e = s;
        for (; e + 4 <= t; e += 4) {
            int j0 = csr_col[e], j1 = csr_col[e + 1], j2 = csr_col[e + 2], j3 = csr_col[e + 3];
            ushort4 v0 = *(const ushort4*)(H + (size_t)j0 * D + lane * 4);
            ushort4 v1 = *(const ushort4*)(H + (size_t)j1 * D + lane * 4);
            ushort4 v2 = *(const ushort4*)(H + (size_t)j2 * D + lane * 4);
            ushort4 v3 = *(const ushort4*)(H + (size_t)j3 * D + lane * 4);
            float d;
            d = hx - bf2f(v0.x); ax += d * d;  d = hy - bf2f(v0.y); ay += d * d;
            d = hz - bf2f(v0.z); az += d * d;  d = hw - bf2f(v0.w); aw += d * d;
            d = hx - bf2f(v1.x); ax += d * d;  d = hy - bf2f(v1.y); ay += d * d;
            d = hz - bf2f(v1.z); az += d * d;  d = hw - bf2f(v1.w); aw += d * d;
            d = hx - bf2f(v2.x); ax += d * d;  d = hy - bf2f(v2.y); ay += d * d;
            d = hz - bf2f(v2.z); az += d * d;  d = hw - bf2f(v2.w); aw += d * d;
            d = hx - bf2f(v3.x); ax += d * d;  d = hy - bf2f(v3.y); ay += d * d;
            d = hz - bf2f(v3.z); az += d * d;  d = hw - bf2f(v3.w); aw += d * d;
        }
        for (; e < t; ++e) {
            int j = csr_col[e];
            ushort4 v = *(const ushort4*)(H + (size_t)j * D + lane * 4);
            float d;
            d = hx - bf2f(v.x); ax += d * d;  d = hy - bf2f(v.y); ay += d * d;
            d = hz - bf2f(v.z); az += d * d;  d = hw - bf2f(v.w); aw += d * d;
        }
    }
    float inv = 1.f / (float)((en - st) > 1 ? (en - st) : 1);
    float4 o;
    o.x = tanhf(ax * inv); o.y = tanhf(ay * inv);
    o.z = tanhf(az * inv); o.w = tanhf(aw * inv);
    *(float4*)(out + (size_t)node * D + lane * 4) = o;
}

// ---------------- launch ----------------

extern "C" void kernel_launch(void* const* d_in, const int* in_sizes, int n_in,
                              void* d_out, int out_size, void* d_ws, size_t ws_size,
                              hipStream_t stream) {
    const float* X    = (const float*)d_in[0];
    const int*   edge = (const int*)d_in[1];
    const float* Wr   = (const float*)d_in[2];
    const float* Wn   = (const float*)d_in[3];
    const float* bias = (const float*)d_in[4];
    float* out = (float*)d_out;

    char* ws = (char*)d_ws;
    size_t off = 0;
    auto alloc = [&](size_t bytes) -> void* {
        void* p = ws + off;
        off += (bytes + 255) & ~(size_t)255;
        return p;
    };
    int*      degcur  = (int*)alloc(sizeof(int) * 3 * N_NODES);   // deg | curLo | curHi
    int*      offsets = (int*)alloc(sizeof(int) * (N_NODES + 1));
    int*      csr_col = (int*)alloc(sizeof(int) * N_EDGES);
    ushort_t* A       = (ushort_t*)alloc(sizeof(ushort_t) * (size_t)N_NODES * KDIM);
    ushort_t* Wb      = (ushort_t*)alloc(sizeof(ushort_t) * (size_t)D * KDIM);
    ushort_t* H       = (ushort_t*)alloc(sizeof(ushort_t) * (size_t)N_NODES * D);

    int* deg   = degcur;
    int* curLo = degcur + N_NODES;
    int* curHi = degcur + 2 * N_NODES;
    const int* row = edge;
    const int* col = edge + N_EDGES;

    k_zero<<<(3 * N_NODES + 255) / 256, 256, 0, stream>>>(degcur, 3 * N_NODES);
    k_prep<<<DEG_BLOCKS + PREPW_BLOCKS + CASTX_BLOCKS, 256, 0, stream>>>(
        row, deg, Wr, Wn, Wb, X, A);
    k_scan<<<1, 1024, 0, stream>>>(deg, offsets);
    k_fill<<<(N_EDGES + 255) / 256, 256, 0, stream>>>(row, col, offsets, curLo, curHi,
                                                      csr_col, N_EDGES);
    k_mean<<<2500, 256, 0, stream>>>(offsets, curLo, csr_col, A);

    dim3 ggrid((N_NODES + BM - 1) / BM, D / BN);
    k_gemm<<<ggrid, 256, 0, stream>>>(A, Wb, bias, H);

    k_out<<<2500, 256, 0, stream>>>(H, offsets, curLo, csr_col, out);
}